// Round 3
// baseline (390.138 us; speedup 1.0000x reference)
//
#include <hip/hip_runtime.h>
#include <hip/hip_fp16.h>
#include <stdint.h>

#define TS 200

typedef _Float16 h2_t  __attribute__((ext_vector_type(2)));
typedef _Float16 f16x8 __attribute__((ext_vector_type(8)));
typedef float    f32x4 __attribute__((ext_vector_type(4)));

static __device__ __forceinline__ float fdot2f(uint32_t w, uint32_t h, float acc) {
#if __has_builtin(__builtin_amdgcn_fdot2)
    return __builtin_amdgcn_fdot2(__builtin_bit_cast(h2_t, w),
                                  __builtin_bit_cast(h2_t, h), acc, false);
#else
    h2_t a = __builtin_bit_cast(h2_t, w), b = __builtin_bit_cast(h2_t, h);
    acc = fmaf((float)a.x, (float)b.x, acc);
    acc = fmaf((float)a.y, (float)b.y, acc);
    return acc;
#endif
}

// DPP add-reduce helper: acc += dpp_move(acc). All lanes active when called.
template <int CTRL>
static __device__ __forceinline__ float dpp_add(float x) {
    int m = __builtin_amdgcn_update_dpp(0, __builtin_bit_cast(int, x), CTRL, 0xF, 0xF, true);
    return x + __builtin_bit_cast(float, m);
}

// ---------------------------------------------------------------------------
// K0: one-time packs.
//  blocks [0,6400):        xh[row=b*200+t][k] = f16(x[b][10t][k])
//  blocks [6400,8448):     wxt[n=c*512+g*256+u][k] = f16(Wx[c][g][k][u])
//  blocks [8448,9472):     wp: W_h fp16 pairs in recurrence thread layout
//                          [c][g][j=16][thr=512][e=4] (uint per (2v,u))
// ---------------------------------------------------------------------------
__global__ __launch_bounds__(256) void pack_all(const float* __restrict__ x,
                                                const float* __restrict__ Wx,
                                                const float* __restrict__ Wh,
                                                _Float16* __restrict__ xh,
                                                _Float16* __restrict__ wxt,
                                                uint32_t* __restrict__ wp) {
    int bid = blockIdx.x, tid = threadIdx.x;
    if (bid < 6400) {
        int row = bid, col = tid;
        int b = row / 200, t = row - b * 200;
        xh[(size_t)row * 256 + col] = (_Float16)x[((size_t)(b * 2000 + t * 10)) * 256 + col];
    } else if (bid < 8448) {
        int n = bid - 6400, k = tid;
        wxt[(size_t)n * 256 + k] = (_Float16)Wx[((size_t)((n >> 8) * 256 + k)) * 256 + (n & 255)];
    } else {
        int idx = (bid - 8448) * 256 + tid;          // [0, 262144)
        int e = idx & 3, thr = (idx >> 2) & 511, j = (idx >> 11) & 15;
        int g = (idx >> 15) & 1, c = idx >> 16;
        int vs = thr & 7, uq = (thr >> 3) & 7, wu = thr >> 6;
        int uu = j >> 2, i = j & 3;
        int u = wu * 32 + uq * 4 + uu;
        int v = vs * 32 + i * 8 + e * 2;
        const float* base = Wh + ((size_t)((c * 2 + g) * 256 + v)) * 256 + u;
        h2_t p; p.x = (_Float16)base[0]; p.y = (_Float16)base[256];
        wp[idx] = __builtin_bit_cast(uint32_t, p);
    }
}

// ---------------------------------------------------------------------------
// K1: xp = X[6400x256] * W[256x2048] + bias, f16 MFMA 16x16x32.
// 128x128 tile, BK=64, 4 waves (each a 64x64 quadrant, 4x4 16x16 tiles).
// ---------------------------------------------------------------------------
__global__ __launch_bounds__(256) void xp_gemm(const _Float16* __restrict__ xh,
                                               const _Float16* __restrict__ wxt,
                                               const float* __restrict__ bxf,
                                               _Float16* __restrict__ xp) {
    __shared__ _Float16 As[128 * 64];
    __shared__ _Float16 Bs[128 * 64];
    const int tid = threadIdx.x;
    const int lane = tid & 63, w = tid >> 6;
    const int m0 = (blockIdx.x >> 4) * 128;
    const int n0 = (blockIdx.x & 15) * 128;
    const int mw = (w & 1) * 64, nw = (w >> 1) * 64;

    f32x4 acc[4][4] = {};

    for (int kb = 0; kb < 4; kb++) {
        const int k0 = kb * 64;
#pragma unroll
        for (int q = 0; q < 4; q++) {
            int ii = w * 4 + q;                       // 0..15 chunk id
            int r = ii * 8 + (lane >> 3);             // row 0..127
            int kcol = (lane & 7) * 8;
            const _Float16* ga = xh  + (size_t)(m0 + r) * 256 + k0 + kcol;
            const _Float16* gb = wxt + (size_t)(n0 + r) * 256 + k0 + kcol;
            __builtin_amdgcn_global_load_lds(
                (const __attribute__((address_space(1))) uint32_t*)ga,
                (__attribute__((address_space(3))) uint32_t*)(As + ii * 512), 16, 0, 0);
            __builtin_amdgcn_global_load_lds(
                (const __attribute__((address_space(1))) uint32_t*)gb,
                (__attribute__((address_space(3))) uint32_t*)(Bs + ii * 512), 16, 0, 0);
        }
        __syncthreads();
#pragma unroll
        for (int kc = 0; kc < 2; kc++) {
            f16x8 a[4], b[4];
#pragma unroll
            for (int mt = 0; mt < 4; mt++)
                a[mt] = *(const f16x8*)&As[(mw + mt * 16 + (lane & 15)) * 64 + kc * 32 + (lane >> 4) * 8];
#pragma unroll
            for (int nt = 0; nt < 4; nt++)
                b[nt] = *(const f16x8*)&Bs[(nw + nt * 16 + (lane & 15)) * 64 + kc * 32 + (lane >> 4) * 8];
#pragma unroll
            for (int mt = 0; mt < 4; mt++)
#pragma unroll
                for (int nt = 0; nt < 4; nt++)
                    acc[mt][nt] = __builtin_amdgcn_mfma_f32_16x16x32_f16(a[mt], b[nt], acc[mt][nt], 0, 0, 0);
        }
        __syncthreads();
    }

    const int nl = lane & 15, quad = lane >> 4;
#pragma unroll
    for (int nt = 0; nt < 4; nt++) {
        int n = n0 + nw + nt * 16 + nl;
        float bias = bxf[n];
        int c = n >> 9, gu = n & 511;
#pragma unroll
        for (int mt = 0; mt < 4; mt++)
#pragma unroll
            for (int r = 0; r < 4; r++) {
                int m = m0 + mw + mt * 16 + quad * 4 + r;
                int b = m / 200, t = m - b * 200;
                xp[((size_t)((c * 32 + b) * 200 + t)) * 512 + gu] =
                    (_Float16)(acc[mt][nt][r] + bias);
            }
    }
}

// ---------------------------------------------------------------------------
// K2: 200-step gated recurrence. 128 WGs (c,b) x 1024 threads.
// Thread (g = tid>>9, wave-u wu, u-quad uq, v-slice vs): 4 u's x 32 v's.
// Weights register-resident (16 uint4 = 64 VGPRs), PINNED via opaque asm so
// the compiler cannot rematerialize the loads inside the t-loop (R2's bug:
// VGPR_Count=44 proved w[] was re-fetched from L2 every step -> L2-BW bound).
// ---------------------------------------------------------------------------
__global__ __launch_bounds__(1024, 4) void recurrence(const _Float16* __restrict__ xp,
                                                      const float* __restrict__ bh,
                                                      const uint32_t* __restrict__ Wp,
                                                      float* __restrict__ hs) {
    const int c = blockIdx.x >> 5;
    const int b = blockIdx.x & 31;
    const int tid = threadIdx.x;
    const int g = tid >> 9;
    const int thr = tid & 511;
    const int lane = tid & 63;
    const int vs = lane & 7;
    const int uq = lane >> 3;
    const int wu = (tid >> 6) & 7;

    __shared__ __align__(16) uint32_t h2s[8 * 20];   // 8 v-slices x 16 uints + 4 pad
    __shared__ float sg[512];                        // [u][g] sigmoid outputs

    // register-resident weights: 16 uint4 = 64 half2 (4 u's x 32 v's)
    uint4 w[16];
    {
        const uint4* wb = (const uint4*)Wp + ((size_t)(c * 2 + g) * 16) * 512 + thr;
#pragma unroll
        for (int j = 0; j < 16; j++) w[j] = wb[(size_t)j * 512];
    }
    // Opaque identity: values become unknowable to the compiler -> cannot be
    // rematerialized by re-loading; must stay live in VGPRs across the loop.
#pragma unroll
    for (int j = 0; j < 16; j++)
        asm volatile("" : "+v"(w[j].x), "+v"(w[j].y), "+v"(w[j].z), "+v"(w[j].w));

    const int u_w = wu * 32 + uq * 4 + vs;           // writer u (valid when vs<4)
    float bias = 0.f;
    const _Float16* xpb = nullptr;
    if (vs < 4) {
        bias = bh[(c * 2 + g) * 256 + u_w];
        xpb = xp + ((size_t)((c * 32 + b) * 200)) * 512 + g * 256 + u_w;
    }

    float hreg = 0.f;                                // thread tid<256 owns h[tid]
    if (tid < 160) h2s[tid] = 0u;
    __syncthreads();

    const size_t hsb = (size_t)((c * 32 + b) * 200) * 256 + tid;

    for (int t = 0; t < TS; t++) {
        float xpv = 0.f;
        if (vs < 4) xpv = (float)xpb[(size_t)t * 512];

        uint4 hh[4];
#pragma unroll
        for (int i = 0; i < 4; i++) hh[i] = *(const uint4*)(h2s + vs * 20 + i * 4);

        float acc[4] = {0.f, 0.f, 0.f, 0.f};
#pragma unroll
        for (int uu = 0; uu < 4; uu++)
#pragma unroll
            for (int i = 0; i < 4; i++) {
                acc[uu] = fdot2f(w[uu * 4 + i].x, hh[i].x, acc[uu]);
                acc[uu] = fdot2f(w[uu * 4 + i].y, hh[i].y, acc[uu]);
                acc[uu] = fdot2f(w[uu * 4 + i].z, hh[i].z, acc[uu]);
                acc[uu] = fdot2f(w[uu * 4 + i].w, hh[i].w, acc[uu]);
            }
#pragma unroll
        for (int uu = 0; uu < 4; uu++) {
            float a = acc[uu];
            a = dpp_add<0xB1>(a);    // quad_perm xor1
            a = dpp_add<0x4E>(a);    // quad_perm xor2
            a = dpp_add<0x141>(a);   // row_half_mirror: l ^ 7 within 8
            acc[uu] = a;
        }
        if (vs < 4) {
            float s = (vs == 0 ? acc[0] : vs == 1 ? acc[1] : vs == 2 ? acc[2] : acc[3])
                      + xpv + bias;
            sg[u_w * 2 + g] = 1.f / (1.f + __expf(-s));
        }
        __syncthreads();
        if (tid < 256) {
            float2 jk = *(const float2*)(sg + tid * 2);
            float hn = jk.x + hreg * (1.f - jk.x - jk.y);
            hreg = hn;
            hs[hsb + (size_t)t * 256] = hn;
            ((_Float16*)h2s)[(tid >> 5) * 40 + (tid & 31)] = (_Float16)hn;
        }
        __syncthreads();
    }
}

// ---------------------------------------------------------------------------
// K3: oscillator expansion (memory-bound).
// ---------------------------------------------------------------------------
__global__ __launch_bounds__(256) void osc(const float* __restrict__ hs,
                                           float* __restrict__ out) {
    int tid = blockIdx.x * 256 + threadIdx.x;   // 1,638,400
    const int cstride = 32 * 200 * 256;
    int u = tid & 255;
    int bt = tid >> 8;
    int t = bt % 200, b = bt / 200;
    float phi   = hs[0 * cstride + tid];
    float omega = hs[1 * cstride + tid];
    float r     = hs[2 * cstride + tid];
    float mu    = hs[3 * cstride + tid];
    float* o = out + ((size_t)(b * 2000 + t * 10)) * 256 + u;
#pragma unroll
    for (int s = 0; s < 10; s++) {
        o[(size_t)s * 256] = r * __cosf(phi);
        r = r + (mu - r * r) * r;
        phi = phi + omega;
    }
}

// ---------------------------------------------------------------------------
extern "C" void kernel_launch(void* const* d_in, const int* in_sizes, int n_in,
                              void* d_out, int out_size, void* d_ws, size_t ws_size,
                              hipStream_t stream) {
    const float* x  = (const float*)d_in[0];
    const float* Wx = (const float*)d_in[1];
    const float* bx = (const float*)d_in[2];
    const float* Wh = (const float*)d_in[3];
    const float* bh = (const float*)d_in[4];
    float* out = (float*)d_out;

    char* ws = (char*)d_ws;
    const size_t XP = (size_t)4 * 32 * 200 * 512 * 2;   // 26.2 MB f16
    const size_t HS = (size_t)4 * 32 * 200 * 256 * 4;   // 26.2 MB f32
    const size_t XH = (size_t)6400 * 256 * 2;           // 3.28 MB

    _Float16* xp  = (_Float16*)ws;
    float*    hs  = (float*)(ws + XP);
    // xh/wxt alias the hs region: they are dead before recurrence writes hs.
    _Float16* xh  = (_Float16*)(ws + XP);
    _Float16* wxt = (_Float16*)(ws + XP + XH);
    uint32_t* wp  = (uint32_t*)(ws + XP + HS);

    pack_all<<<9472, 256, 0, stream>>>(x, Wx, Wh, xh, wxt, wp);
    xp_gemm<<<800, 256, 0, stream>>>(xh, wxt, bx, xp);
    recurrence<<<128, 1024, 0, stream>>>(xp, bh, wp, hs);
    osc<<<6400, 256, 0, stream>>>(hs, out);
}

// Round 4
// 374.166 us; speedup vs baseline: 1.0427x; 1.0427x over previous
//
#include <hip/hip_runtime.h>
#include <hip/hip_fp16.h>
#include <stdint.h>

#define TS 200

typedef _Float16 h2_t  __attribute__((ext_vector_type(2)));
typedef _Float16 f16x8 __attribute__((ext_vector_type(8)));
typedef float    f32x4 __attribute__((ext_vector_type(4)));

static __device__ __forceinline__ float fdot2f(uint32_t w, uint32_t h, float acc) {
#if __has_builtin(__builtin_amdgcn_fdot2)
    return __builtin_amdgcn_fdot2(__builtin_bit_cast(h2_t, w),
                                  __builtin_bit_cast(h2_t, h), acc, false);
#else
    h2_t a = __builtin_bit_cast(h2_t, w), b = __builtin_bit_cast(h2_t, h);
    acc = fmaf((float)a.x, (float)b.x, acc);
    acc = fmaf((float)a.y, (float)b.y, acc);
    return acc;
#endif
}

template <int CTRL>
static __device__ __forceinline__ float dpp_add(float x) {
    int m = __builtin_amdgcn_update_dpp(0, __builtin_bit_cast(int, x), CTRL, 0xF, 0xF, true);
    return x + __builtin_bit_cast(float, m);
}
template <int CTRL>
static __device__ __forceinline__ float dpp_mov(float x) {
    int m = __builtin_amdgcn_update_dpp(0, __builtin_bit_cast(int, x), CTRL, 0xF, 0xF, true);
    return __builtin_bit_cast(float, m);
}

// ---------------------------------------------------------------------------
// K0: one-time packs.
//  blocks [0,6400):     xh[row=b*200+t][k] = f16(x[b][10t][k])
//  blocks [6400,8448):  wxt[n=c*512+g*256+u][k] = f16(Wx[c][g][k][u])
//  blocks [8448,9472):  wp: W_h fp16 pairs, recurrence thread layout
//                       [c][j=16][thr=1024][e=4]; j=a*4+i, a=uu*2+g;
//                       thr=(wv*8+uq)*8... thr= wv*64+uq*8+vs; value =
//                       half2(Wh[c][g][v][u], Wh[c][g][v+1][u]),
//                       u=(wv*8+uq)*2+uu, v=vs*32+i*8+e*2.
// ---------------------------------------------------------------------------
__global__ __launch_bounds__(256) void pack_all(const float* __restrict__ x,
                                                const float* __restrict__ Wx,
                                                const float* __restrict__ Wh,
                                                _Float16* __restrict__ xh,
                                                _Float16* __restrict__ wxt,
                                                uint32_t* __restrict__ wp) {
    int bid = blockIdx.x, tid = threadIdx.x;
    if (bid < 6400) {
        int row = bid, col = tid;
        int b = row / 200, t = row - b * 200;
        xh[(size_t)row * 256 + col] = (_Float16)x[((size_t)(b * 2000 + t * 10)) * 256 + col];
    } else if (bid < 8448) {
        int n = bid - 6400, k = tid;
        wxt[(size_t)n * 256 + k] = (_Float16)Wx[((size_t)((n >> 8) * 256 + k)) * 256 + (n & 255)];
    } else {
        int idx = (bid - 8448) * 256 + tid;          // [0, 262144)
        int e   = idx & 3;
        int thr = (idx >> 2) & 1023;
        int j   = (idx >> 12) & 15;
        int c   = idx >> 16;
        int a = j >> 2, i = j & 3;
        int uu = a >> 1, g = a & 1;
        int vs = thr & 7, uq = (thr >> 3) & 7, wv = thr >> 6;
        int u = (wv * 8 + uq) * 2 + uu;
        int v = vs * 32 + i * 8 + e * 2;
        const float* base = Wh + ((size_t)((c * 2 + g) * 256 + v)) * 256 + u;
        h2_t p; p.x = (_Float16)base[0]; p.y = (_Float16)base[256];
        wp[idx] = __builtin_bit_cast(uint32_t, p);
    }
}

// ---------------------------------------------------------------------------
// K1: xp = X[6400x256] * W[256x2048] + bias, f16 MFMA 16x16x32. (unchanged)
// ---------------------------------------------------------------------------
__global__ __launch_bounds__(256) void xp_gemm(const _Float16* __restrict__ xh,
                                               const _Float16* __restrict__ wxt,
                                               const float* __restrict__ bxf,
                                               _Float16* __restrict__ xp) {
    __shared__ _Float16 As[128 * 64];
    __shared__ _Float16 Bs[128 * 64];
    const int tid = threadIdx.x;
    const int lane = tid & 63, w = tid >> 6;
    const int m0 = (blockIdx.x >> 4) * 128;
    const int n0 = (blockIdx.x & 15) * 128;
    const int mw = (w & 1) * 64, nw = (w >> 1) * 64;

    f32x4 acc[4][4] = {};

    for (int kb = 0; kb < 4; kb++) {
        const int k0 = kb * 64;
#pragma unroll
        for (int q = 0; q < 4; q++) {
            int ii = w * 4 + q;
            int r = ii * 8 + (lane >> 3);
            int kcol = (lane & 7) * 8;
            const _Float16* ga = xh  + (size_t)(m0 + r) * 256 + k0 + kcol;
            const _Float16* gb = wxt + (size_t)(n0 + r) * 256 + k0 + kcol;
            __builtin_amdgcn_global_load_lds(
                (const __attribute__((address_space(1))) uint32_t*)ga,
                (__attribute__((address_space(3))) uint32_t*)(As + ii * 512), 16, 0, 0);
            __builtin_amdgcn_global_load_lds(
                (const __attribute__((address_space(1))) uint32_t*)gb,
                (__attribute__((address_space(3))) uint32_t*)(Bs + ii * 512), 16, 0, 0);
        }
        __syncthreads();
#pragma unroll
        for (int kc = 0; kc < 2; kc++) {
            f16x8 a[4], b[4];
#pragma unroll
            for (int mt = 0; mt < 4; mt++)
                a[mt] = *(const f16x8*)&As[(mw + mt * 16 + (lane & 15)) * 64 + kc * 32 + (lane >> 4) * 8];
#pragma unroll
            for (int nt = 0; nt < 4; nt++)
                b[nt] = *(const f16x8*)&Bs[(nw + nt * 16 + (lane & 15)) * 64 + kc * 32 + (lane >> 4) * 8];
#pragma unroll
            for (int mt = 0; mt < 4; mt++)
#pragma unroll
                for (int nt = 0; nt < 4; nt++)
                    acc[mt][nt] = __builtin_amdgcn_mfma_f32_16x16x32_f16(a[mt], b[nt], acc[mt][nt], 0, 0, 0);
        }
        __syncthreads();
    }

    const int nl = lane & 15, quad = lane >> 4;
#pragma unroll
    for (int nt = 0; nt < 4; nt++) {
        int n = n0 + nw + nt * 16 + nl;
        float bias = bxf[n];
        int c = n >> 9, gu = n & 511;
#pragma unroll
        for (int mt = 0; mt < 4; mt++)
#pragma unroll
            for (int r = 0; r < 4; r++) {
                int m = m0 + mw + mt * 16 + quad * 4 + r;
                int b = m / 200, t = m - b * 200;
                xp[((size_t)((c * 32 + b) * 200 + t)) * 512 + gu] =
                    (_Float16)(acc[mt][nt][r] + bias);
            }
    }
}

// ---------------------------------------------------------------------------
// K2: 200-step gated recurrence. 128 WGs (c,b) x 1024 threads, 1 WG/CU.
// Thread (wv=tid>>6, uq=(lane>>3), vs=lane&7) owns u-pair (wv*8+uq)*2{+0,1},
// BOTH gates, v-slice [vs*32, vs*32+32): 64 half2 weights = 64 VGPRs,
// forced resident by amdgpu_waves_per_eu(4,4) (exact 128-VGPR budget) +
// opaque asm pin. One barrier/step via double-buffered h2s + DPP gate
// exchange (no sg[] roundtrip).
// ---------------------------------------------------------------------------
__global__ __attribute__((amdgpu_flat_work_group_size(1024, 1024),
                          amdgpu_waves_per_eu(4, 4)))
void recurrence(const _Float16* __restrict__ xp,
                const float* __restrict__ bh,
                const uint32_t* __restrict__ Wp,
                float* __restrict__ hs) {
    const int cb  = blockIdx.x;            // c*32+b
    const int c   = cb >> 5;
    const int tid = threadIdx.x;
    const int lane = tid & 63;
    const int vs = lane & 7;
    const int uq = lane >> 3;
    const int wv = tid >> 6;
    const int upair = wv * 8 + uq;         // 0..127
    const int u0 = upair * 2;

    // h2s double buffer: 2 x (8 slices x 20 words) — stride-20 bank partition
    __shared__ __align__(16) uint32_t h2s[2][160];

    // register-resident weights: 16 uint4 = 64 half2 (2u x 2g x 32v)
    uint4 w[16];
    {
        const uint4* wb = (const uint4*)Wp + (size_t)c * 16 * 1024 + tid;
#pragma unroll
        for (int j = 0; j < 16; j++) w[j] = wb[(size_t)j * 1024];
    }
#pragma unroll
    for (int j = 0; j < 16; j++)
        asm volatile("" : "+v"(w[j].x), "+v"(w[j].y), "+v"(w[j].z), "+v"(w[j].w));

    // xp / bias for reduce lanes (vs<4): (u = u0 + (vs>>1), g = vs&1)
    float bias = 0.f;
    const _Float16* xpb = nullptr;
    if (vs < 4) {
        int g_sel = vs & 1, u_sel = u0 + (vs >> 1);
        bias = bh[(c * 2 + g_sel) * 256 + u_sel];
        xpb  = xp + (size_t)cb * 200 * 512 + g_sel * 256 + u_sel;
    }

    float hreg = 0.f;                      // valid at vs==0 (u0) and vs==2 (u1)
    if (tid < 160) { h2s[0][tid] = 0u; }
    __syncthreads();

    float* hsb = hs + (size_t)cb * 200 * 256 + u0;

    const uint32_t* wf = (const uint32_t*)w;

    for (int t = 0; t < TS; t++) {
        const uint32_t* hbuf = h2s[t & 1];
        uint32_t* hnext = h2s[(t + 1) & 1];

        float xpv = 0.f;
        if (vs < 4) xpv = (float)xpb[(size_t)t * 512];

        uint4 hh[4];
#pragma unroll
        for (int i = 0; i < 4; i++) hh[i] = *(const uint4*)(hbuf + vs * 20 + i * 4);
        const uint32_t* hf = (const uint32_t*)hh;

        float acc[4] = {0.f, 0.f, 0.f, 0.f};   // a = uu*2+g
#pragma unroll
        for (int i = 0; i < 4; i++)
#pragma unroll
            for (int cmp = 0; cmp < 4; cmp++)
#pragma unroll
                for (int a = 0; a < 4; a++)
                    acc[a] = fdot2f(wf[(a * 4 + i) * 4 + cmp], hf[i * 4 + cmp], acc[a]);

#pragma unroll
        for (int a = 0; a < 4; a++) {
            float v = acc[a];
            v = dpp_add<0xB1>(v);    // quad_perm xor1
            v = dpp_add<0x4E>(v);    // quad_perm xor2
            v = dpp_add<0x141>(v);   // row_half_mirror: l^7 within 8
            acc[a] = v;
        }
        // lane vs -> acc index: vs0:(u0,j) vs1:(u0,k) vs2:(u1,j) vs3:(u1,k)
        float s = (vs == 0) ? acc[0] : (vs == 1) ? acc[1] : (vs == 2) ? acc[2] : acc[3];
        s += xpv + bias;
        float sig = 1.f / (1.f + __expf(-s));
        // gate exchange: even-vs lanes pull partner's k-gate
        float kg = dpp_mov<0xB1>(sig);                 // xor1
        float hn = sig + hreg * (1.f - sig - kg);      // valid at vs0 (u0), vs2 (u1)
        hreg = hn;
        float hn1 = dpp_mov<0x4E>(hn);                 // u1's hn -> vs0
        if (vs == 0) {
            h2_t p; p.x = (_Float16)hn; p.y = (_Float16)hn1;
            hnext[(upair >> 4) * 20 + (upair & 15)] = __builtin_bit_cast(uint32_t, p);
            *(float2*)(hsb + (size_t)t * 256) = make_float2(hn, hn1);
        }
        __syncthreads();
    }
}

// ---------------------------------------------------------------------------
// K3: oscillator expansion (memory-bound). (unchanged)
// ---------------------------------------------------------------------------
__global__ __launch_bounds__(256) void osc(const float* __restrict__ hs,
                                           float* __restrict__ out) {
    int tid = blockIdx.x * 256 + threadIdx.x;   // 1,638,400
    const int cstride = 32 * 200 * 256;
    int u = tid & 255;
    int bt = tid >> 8;
    int t = bt % 200, b = bt / 200;
    float phi   = hs[0 * cstride + tid];
    float omega = hs[1 * cstride + tid];
    float r     = hs[2 * cstride + tid];
    float mu    = hs[3 * cstride + tid];
    float* o = out + ((size_t)(b * 2000 + t * 10)) * 256 + u;
#pragma unroll
    for (int s = 0; s < 10; s++) {
        o[(size_t)s * 256] = r * __cosf(phi);
        r = r + (mu - r * r) * r;
        phi = phi + omega;
    }
}

// ---------------------------------------------------------------------------
extern "C" void kernel_launch(void* const* d_in, const int* in_sizes, int n_in,
                              void* d_out, int out_size, void* d_ws, size_t ws_size,
                              hipStream_t stream) {
    const float* x  = (const float*)d_in[0];
    const float* Wx = (const float*)d_in[1];
    const float* bx = (const float*)d_in[2];
    const float* Wh = (const float*)d_in[3];
    const float* bh = (const float*)d_in[4];
    float* out = (float*)d_out;

    char* ws = (char*)d_ws;
    const size_t XP = (size_t)4 * 32 * 200 * 512 * 2;   // 26.2 MB f16
    const size_t HS = (size_t)4 * 32 * 200 * 256 * 4;   // 26.2 MB f32
    const size_t XH = (size_t)6400 * 256 * 2;           // 3.28 MB

    _Float16* xp  = (_Float16*)ws;
    float*    hs  = (float*)(ws + XP);
    // xh/wxt alias the hs region: they are dead before recurrence writes hs.
    _Float16* xh  = (_Float16*)(ws + XP);
    _Float16* wxt = (_Float16*)(ws + XP + XH);
    uint32_t* wp  = (uint32_t*)(ws + XP + HS);

    pack_all<<<9472, 256, 0, stream>>>(x, Wx, Wh, xh, wxt, wp);
    xp_gemm<<<800, 256, 0, stream>>>(xh, wxt, bx, xp);
    recurrence<<<128, 1024, 0, stream>>>(xp, bh, wp, hs);
    osc<<<6400, 256, 0, stream>>>(hs, out);
}

// Round 6
// 372.363 us; speedup vs baseline: 1.0477x; 1.0048x over previous
//
#include <hip/hip_runtime.h>
#include <hip/hip_fp16.h>
#include <stdint.h>

#define TS 200

typedef _Float16 h2_t  __attribute__((ext_vector_type(2)));
typedef _Float16 f16x8 __attribute__((ext_vector_type(8)));
typedef float    f32x4 __attribute__((ext_vector_type(4)));

static __device__ __forceinline__ float fdot2f(uint32_t w, uint32_t h, float acc) {
#if __has_builtin(__builtin_amdgcn_fdot2)
    return __builtin_amdgcn_fdot2(__builtin_bit_cast(h2_t, w),
                                  __builtin_bit_cast(h2_t, h), acc, false);
#else
    h2_t a = __builtin_bit_cast(h2_t, w), b = __builtin_bit_cast(h2_t, h);
    acc = fmaf((float)a.x, (float)b.x, acc);
    acc = fmaf((float)a.y, (float)b.y, acc);
    return acc;
#endif
}

template <int CTRL>
static __device__ __forceinline__ float dpp_add(float x) {
    int m = __builtin_amdgcn_update_dpp(0, __builtin_bit_cast(int, x), CTRL, 0xF, 0xF, true);
    return x + __builtin_bit_cast(float, m);
}
template <int CTRL>
static __device__ __forceinline__ float dpp_mov(float x) {
    int m = __builtin_amdgcn_update_dpp(0, __builtin_bit_cast(int, x), CTRL, 0xF, 0xF, true);
    return __builtin_bit_cast(float, m);
}

// ---------------------------------------------------------------------------
// K0: one-time packs (unchanged).
//  blocks [0,6400):     xh[row=b*200+t][k] = f16(x[b][10t][k])
//  blocks [6400,8448):  wxt[n=c*512+g*256+u][k] = f16(Wx[c][g][k][u])
//  blocks [8448,9472):  wp: W_h fp16 pairs, recurrence thread layout
//                       [c][j=16][thr=1024][e=4]; j=a*4+i, a=uu*2+g;
//                       u=(wv*8+uq)*2+uu, v=vs*32+i*8+e*2, thr=wv*64+uq*8+vs.
// ---------------------------------------------------------------------------
__global__ __launch_bounds__(256) void pack_all(const float* __restrict__ x,
                                                const float* __restrict__ Wx,
                                                const float* __restrict__ Wh,
                                                _Float16* __restrict__ xh,
                                                _Float16* __restrict__ wxt,
                                                uint32_t* __restrict__ wp) {
    int bid = blockIdx.x, tid = threadIdx.x;
    if (bid < 6400) {
        int row = bid, col = tid;
        int b = row / 200, t = row - b * 200;
        xh[(size_t)row * 256 + col] = (_Float16)x[((size_t)(b * 2000 + t * 10)) * 256 + col];
    } else if (bid < 8448) {
        int n = bid - 6400, k = tid;
        wxt[(size_t)n * 256 + k] = (_Float16)Wx[((size_t)((n >> 8) * 256 + k)) * 256 + (n & 255)];
    } else {
        int idx = (bid - 8448) * 256 + tid;          // [0, 262144)
        int e   = idx & 3;
        int thr = (idx >> 2) & 1023;
        int j   = (idx >> 12) & 15;
        int c   = idx >> 16;
        int a = j >> 2, i = j & 3;
        int uu = a >> 1, g = a & 1;
        int vs = thr & 7, uq = (thr >> 3) & 7, wv = thr >> 6;
        int u = (wv * 8 + uq) * 2 + uu;
        int v = vs * 32 + i * 8 + e * 2;
        const float* base = Wh + ((size_t)((c * 2 + g) * 256 + v)) * 256 + u;
        h2_t p; p.x = (_Float16)base[0]; p.y = (_Float16)base[256];
        wp[idx] = __builtin_bit_cast(uint32_t, p);
    }
}

// ---------------------------------------------------------------------------
// K1: xp = X[6400x256] * W[256x2048] + bias, f16 MFMA 16x16x32. (unchanged)
// ---------------------------------------------------------------------------
__global__ __launch_bounds__(256) void xp_gemm(const _Float16* __restrict__ xh,
                                               const _Float16* __restrict__ wxt,
                                               const float* __restrict__ bxf,
                                               _Float16* __restrict__ xp) {
    __shared__ _Float16 As[128 * 64];
    __shared__ _Float16 Bs[128 * 64];
    const int tid = threadIdx.x;
    const int lane = tid & 63, w = tid >> 6;
    const int m0 = (blockIdx.x >> 4) * 128;
    const int n0 = (blockIdx.x & 15) * 128;
    const int mw = (w & 1) * 64, nw = (w >> 1) * 64;

    f32x4 acc[4][4] = {};

    for (int kb = 0; kb < 4; kb++) {
        const int k0 = kb * 64;
#pragma unroll
        for (int q = 0; q < 4; q++) {
            int ii = w * 4 + q;
            int r = ii * 8 + (lane >> 3);
            int kcol = (lane & 7) * 8;
            const _Float16* ga = xh  + (size_t)(m0 + r) * 256 + k0 + kcol;
            const _Float16* gb = wxt + (size_t)(n0 + r) * 256 + k0 + kcol;
            __builtin_amdgcn_global_load_lds(
                (const __attribute__((address_space(1))) uint32_t*)ga,
                (__attribute__((address_space(3))) uint32_t*)(As + ii * 512), 16, 0, 0);
            __builtin_amdgcn_global_load_lds(
                (const __attribute__((address_space(1))) uint32_t*)gb,
                (__attribute__((address_space(3))) uint32_t*)(Bs + ii * 512), 16, 0, 0);
        }
        __syncthreads();
#pragma unroll
        for (int kc = 0; kc < 2; kc++) {
            f16x8 a[4], b[4];
#pragma unroll
            for (int mt = 0; mt < 4; mt++)
                a[mt] = *(const f16x8*)&As[(mw + mt * 16 + (lane & 15)) * 64 + kc * 32 + (lane >> 4) * 8];
#pragma unroll
            for (int nt = 0; nt < 4; nt++)
                b[nt] = *(const f16x8*)&Bs[(nw + nt * 16 + (lane & 15)) * 64 + kc * 32 + (lane >> 4) * 8];
#pragma unroll
            for (int mt = 0; mt < 4; mt++)
#pragma unroll
                for (int nt = 0; nt < 4; nt++)
                    acc[mt][nt] = __builtin_amdgcn_mfma_f32_16x16x32_f16(a[mt], b[nt], acc[mt][nt], 0, 0, 0);
        }
        __syncthreads();
    }

    const int nl = lane & 15, quad = lane >> 4;
#pragma unroll
    for (int nt = 0; nt < 4; nt++) {
        int n = n0 + nw + nt * 16 + nl;
        float bias = bxf[n];
        int c = n >> 9, gu = n & 511;
#pragma unroll
        for (int mt = 0; mt < 4; mt++)
#pragma unroll
            for (int r = 0; r < 4; r++) {
                int m = m0 + mw + mt * 16 + quad * 4 + r;
                int b = m / 200, t = m - b * 200;
                xp[((size_t)((c * 32 + b) * 200 + t)) * 512 + gu] =
                    (_Float16)(acc[mt][nt][r] + bias);
            }
    }
}

// ---------------------------------------------------------------------------
// K2: 200-step gated recurrence. 128 WGs (c,b) x 1024 threads, 1 WG/CU.
// Weights: 16 NAMED uint4 variables (SSA, nothing addressable -> no alloca),
// pinned by per-SCALAR-component volatile asm (tied 128-bit operands don't
// compile on gfx950; the scalar form does — proven in R3). waves_per_eu(4,4)
// gives an exact 128-VGPR budget; live set ~105 regs fits.
// ---------------------------------------------------------------------------
#define D4(ACC, W, H)                 \
    ACC = fdot2f(W.x, H.x, ACC);      \
    ACC = fdot2f(W.y, H.y, ACC);      \
    ACC = fdot2f(W.z, H.z, ACC);      \
    ACC = fdot2f(W.w, H.w, ACC);

#define PIN4(W) asm volatile("" : "+v"(W.x), "+v"(W.y), "+v"(W.z), "+v"(W.w))

__global__ __attribute__((amdgpu_flat_work_group_size(1024, 1024),
                          amdgpu_waves_per_eu(4, 4)))
void recurrence(const _Float16* __restrict__ xp,
                const float* __restrict__ bh,
                const uint32_t* __restrict__ Wp,
                float* __restrict__ hs) {
    const int cb  = blockIdx.x;            // c*32+b
    const int c   = cb >> 5;
    const int tid = threadIdx.x;
    const int lane = tid & 63;
    const int vs = lane & 7;
    const int uq = lane >> 3;
    const int wv = tid >> 6;
    const int upair = wv * 8 + uq;         // 0..127
    const int u0 = upair * 2;

    // h2s double buffer: 2 x (8 slices x 20 words) — stride-20 bank partition
    __shared__ __align__(16) uint32_t h2s[2][160];

    // 16 named uint4 weights = 64 half2 (a=uu*2+g in 0..3, i in 0..3)
    const uint4* wb = (const uint4*)Wp + (size_t)c * 16 * 1024 + tid;
    uint4 w00 = wb[0 * 1024],  w01 = wb[1 * 1024],  w02 = wb[2 * 1024],  w03 = wb[3 * 1024];
    uint4 w10 = wb[4 * 1024],  w11 = wb[5 * 1024],  w12 = wb[6 * 1024],  w13 = wb[7 * 1024];
    uint4 w20 = wb[8 * 1024],  w21 = wb[9 * 1024],  w22 = wb[10 * 1024], w23 = wb[11 * 1024];
    uint4 w30 = wb[12 * 1024], w31 = wb[13 * 1024], w32 = wb[14 * 1024], w33 = wb[15 * 1024];
    PIN4(w00); PIN4(w01); PIN4(w02); PIN4(w03);
    PIN4(w10); PIN4(w11); PIN4(w12); PIN4(w13);
    PIN4(w20); PIN4(w21); PIN4(w22); PIN4(w23);
    PIN4(w30); PIN4(w31); PIN4(w32); PIN4(w33);

    // xp / bias for reduce lanes (vs<4): (u = u0 + (vs>>1), g = vs&1)
    float bias = 0.f;
    const _Float16* xpb = nullptr;
    if (vs < 4) {
        int g_sel = vs & 1, u_sel = u0 + (vs >> 1);
        bias = bh[(c * 2 + g_sel) * 256 + u_sel];
        xpb  = xp + (size_t)cb * 200 * 512 + g_sel * 256 + u_sel;
    }

    float hreg = 0.f;                      // valid at vs==0 (u0) and vs==2 (u1)
    if (tid < 160) { h2s[0][tid] = 0u; }
    __syncthreads();

    float* hsb = hs + (size_t)cb * 200 * 256 + u0;

    for (int t = 0; t < TS; t++) {
        const uint32_t* hbuf = h2s[t & 1];
        uint32_t* hnext = h2s[(t + 1) & 1];

        float xpv = 0.f;
        if (vs < 4) xpv = (float)xpb[(size_t)t * 512];

        uint4 h0 = *(const uint4*)(hbuf + vs * 20 + 0);
        uint4 h1 = *(const uint4*)(hbuf + vs * 20 + 4);
        uint4 h2 = *(const uint4*)(hbuf + vs * 20 + 8);
        uint4 h3 = *(const uint4*)(hbuf + vs * 20 + 12);

        float acc0 = 0.f, acc1 = 0.f, acc2 = 0.f, acc3 = 0.f;
        D4(acc0, w00, h0) D4(acc1, w10, h0) D4(acc2, w20, h0) D4(acc3, w30, h0)
        D4(acc0, w01, h1) D4(acc1, w11, h1) D4(acc2, w21, h1) D4(acc3, w31, h1)
        D4(acc0, w02, h2) D4(acc1, w12, h2) D4(acc2, w22, h2) D4(acc3, w32, h2)
        D4(acc0, w03, h3) D4(acc1, w13, h3) D4(acc2, w23, h3) D4(acc3, w33, h3)

        acc0 = dpp_add<0x141>(dpp_add<0x4E>(dpp_add<0xB1>(acc0)));
        acc1 = dpp_add<0x141>(dpp_add<0x4E>(dpp_add<0xB1>(acc1)));
        acc2 = dpp_add<0x141>(dpp_add<0x4E>(dpp_add<0xB1>(acc2)));
        acc3 = dpp_add<0x141>(dpp_add<0x4E>(dpp_add<0xB1>(acc3)));

        // lane vs -> acc index: vs0:(u0,j) vs1:(u0,k) vs2:(u1,j) vs3:(u1,k)
        float s = (vs == 0) ? acc0 : (vs == 1) ? acc1 : (vs == 2) ? acc2 : acc3;
        s += xpv + bias;
        float sig = 1.f / (1.f + __expf(-s));
        // gate exchange: even-vs lanes pull partner's k-gate
        float kg = dpp_mov<0xB1>(sig);                 // xor1
        float hn = sig + hreg * (1.f - sig - kg);      // valid at vs0 (u0), vs2 (u1)
        hreg = hn;
        float hn1 = dpp_mov<0x4E>(hn);                 // u1's hn -> vs0
        if (vs == 0) {
            h2_t p; p.x = (_Float16)hn; p.y = (_Float16)hn1;
            hnext[(upair >> 4) * 20 + (upair & 15)] = __builtin_bit_cast(uint32_t, p);
            *(float2*)(hsb + (size_t)t * 256) = make_float2(hn, hn1);
        }
        __syncthreads();
    }
}

// ---------------------------------------------------------------------------
// K3: oscillator expansion (memory-bound). (unchanged)
// ---------------------------------------------------------------------------
__global__ __launch_bounds__(256) void osc(const float* __restrict__ hs,
                                           float* __restrict__ out) {
    int tid = blockIdx.x * 256 + threadIdx.x;   // 1,638,400
    const int cstride = 32 * 200 * 256;
    int u = tid & 255;
    int bt = tid >> 8;
    int t = bt % 200, b = bt / 200;
    float phi   = hs[0 * cstride + tid];
    float omega = hs[1 * cstride + tid];
    float r     = hs[2 * cstride + tid];
    float mu    = hs[3 * cstride + tid];
    float* o = out + ((size_t)(b * 2000 + t * 10)) * 256 + u;
#pragma unroll
    for (int s = 0; s < 10; s++) {
        o[(size_t)s * 256] = r * __cosf(phi);
        r = r + (mu - r * r) * r;
        phi = phi + omega;
    }
}

// ---------------------------------------------------------------------------
extern "C" void kernel_launch(void* const* d_in, const int* in_sizes, int n_in,
                              void* d_out, int out_size, void* d_ws, size_t ws_size,
                              hipStream_t stream) {
    const float* x  = (const float*)d_in[0];
    const float* Wx = (const float*)d_in[1];
    const float* bx = (const float*)d_in[2];
    const float* Wh = (const float*)d_in[3];
    const float* bh = (const float*)d_in[4];
    float* out = (float*)d_out;

    char* ws = (char*)d_ws;
    const size_t XP = (size_t)4 * 32 * 200 * 512 * 2;   // 26.2 MB f16
    const size_t HS = (size_t)4 * 32 * 200 * 256 * 4;   // 26.2 MB f32
    const size_t XH = (size_t)6400 * 256 * 2;           // 3.28 MB

    _Float16* xp  = (_Float16*)ws;
    float*    hs  = (float*)(ws + XP);
    // xh/wxt alias the hs region: they are dead before recurrence writes hs.
    _Float16* xh  = (_Float16*)(ws + XP);
    _Float16* wxt = (_Float16*)(ws + XP + XH);
    uint32_t* wp  = (uint32_t*)(ws + XP + HS);

    pack_all<<<9472, 256, 0, stream>>>(x, Wx, Wh, xh, wxt, wp);
    xp_gemm<<<800, 256, 0, stream>>>(xh, wxt, bx, xp);
    recurrence<<<128, 1024, 0, stream>>>(xp, bh, wp, hs);
    osc<<<6400, 256, 0, stream>>>(hs, out);
}